// Round 10
// baseline (366.726 us; speedup 1.0000x reference)
//
#include <hip/hip_runtime.h>
#include <stdint.h>

#define EMB_DIM 192
#define CDIM 32
#define TDIM 4
#define N_Y 50000
#define N_X 32768
#define KNBR 8
#define ECNT (N_X*KNBR)  // 262144

#define ES  200          // prep embed stage stride (shorts)

// per-wave LDS patch: 16 rows x 264 shorts (row stride 264 -> 16B-aligned b128 rows)
#define PS  264
#define PBYTES (16*PS*2)   // 8448
// kern sub-layout inside patch (fp32 col-major): kf[col*20 + row], 32x20x4=2560 B
#define KFS 20

// prep_all block ranges
#define PREP_TW 272
#define PREP_Y0 PREP_TW
#define PREP_X0 (PREP_TW + 782)
#define PREP_NB (PREP_TW + 782 + 512)

typedef __attribute__((ext_vector_type(8))) short bf16x8;
typedef __attribute__((ext_vector_type(4))) float f32x4;

static __device__ __forceinline__ short f2bf(float f){
  unsigned u = __float_as_uint(f);
  return (short)((u + 0x7FFFu) >> 16);
}
static __device__ __forceinline__ unsigned pk_bf16(float lo, float hi){
  return ((__float_as_uint(lo) + 0x7FFFu) >> 16) |
         ((((__float_as_uint(hi) + 0x7FFFu) >> 16)) << 16);
}
static __device__ __forceinline__ float geluf(float x){
  float x2 = x * x;
  float u  = __builtin_fmaf(0.044715f, x2, 1.0f);
  float p  = x * -1.5957691216057308f;      // -2*0.7978845608
  float e  = __expf(p * u);                 // exp(-2t)
  return x * __builtin_amdgcn_rcpf(1.0f + e);
}

// ---- ONE prep kernel (R9, proven): transpose w1/w2/w3 + precompute c_y/c_x ----
__global__ __launch_bounds__(256, 2) void prep_all(
    const float* __restrict__ ypts, const float* __restrict__ xpts,
    const float* __restrict__ W0, const float* __restrict__ b0,
    const float* __restrict__ W1, const float* __restrict__ W2,
    const float* __restrict__ W3,
    short* __restrict__ w1t, short* __restrict__ w2t, short* __restrict__ w3t,
    short* __restrict__ c_y, float* __restrict__ c_x)
{
  const int tid = threadIdx.x;
  if (blockIdx.x < PREP_TW) {
    int id = blockIdx.x * 256 + tid;
    if (id < 32768) {                     // w1t[n*128+k] = W1[k][n] (128x256)
      int n = id >> 7, k = id & 127;
      w1t[id] = f2bf(W1[k * 256 + n]);
    } else if (id < 65536) {              // w2t[n*256+k] = W2[k][n] (256x128)
      int loc = id - 32768; int n = loc >> 8, k = loc & 255;
      w2t[loc] = f2bf(W2[k * 128 + n]);
    } else if (id < 69632) {              // w3t[n*128+k] = W3[k][n] (128x32)
      int loc = id - 65536; int n = loc >> 7, k = loc & 127;
      w3t[loc] = f2bf(W3[k * 32 + n]);
    }
    return;
  }

  __shared__ __attribute__((aligned(16))) short s_e[64 * ES];
  const bool isY = blockIdx.x < PREP_X0;
  const int row0 = isY ? (blockIdx.x - PREP_Y0) * 64 : (blockIdx.x - PREP_X0) * 64;
  const int wave = tid >> 6, lane = tid & 63;
  const int quad = lane >> 4, l15 = lane & 15;
  const float* W0h = W0 + (isY ? 0 : 192 * 128);

  short bv[2][48];
  #pragma unroll
  for (int nt = 0; nt < 2; ++nt) {
    int n = wave * 32 + nt * 16 + l15;
    #pragma unroll
    for (int ch = 0; ch < 6; ++ch)
      #pragma unroll
      for (int j = 0; j < 8; ++j)
        bv[nt][ch * 8 + j] = f2bf(W0h[(size_t)(ch * 32 + quad * 8 + j) * 128 + n]);
  }

  {
    const int r = tid >> 2, q = tid & 3;
    const int grow = row0 + r;
    const bool valid = isY ? (grow < N_Y) : true;
    const float* src = isY ? (ypts + (size_t)grow * 3) : (xpts + (size_t)grow * 3);
    float c[3] = {0.f, 0.f, 0.f};
    if (valid) { c[0] = src[0]; c[1] = src[1]; c[2] = src[2]; }
    #pragma unroll
    for (int j = 0; j < 24; ++j) {
      int p = q * 24 + j;
      int d = p >> 5, i = p & 31;
      float f = __expf(-0.28782313662425575f * (float)i);   // (1e-4)^(i/32)
      float rev = c[d] * f * 0.15915494309189535f;
      float s  = __builtin_amdgcn_sinf(rev);
      float co = __builtin_amdgcn_cosf(rev);
      *(unsigned*)&s_e[r * ES + d * 64 + 2 * i] = pk_bf16(s, co);
    }
  }
  __syncthreads();

  f32x4 acc[4][2];
  #pragma unroll
  for (int mt = 0; mt < 4; ++mt)
    #pragma unroll
    for (int nt = 0; nt < 2; ++nt) acc[mt][nt] = (f32x4){0.f, 0.f, 0.f, 0.f};
  #pragma unroll
  for (int ch = 0; ch < 6; ++ch) {
    bf16x8 a[4];
    #pragma unroll
    for (int mt = 0; mt < 4; ++mt)
      a[mt] = *(const bf16x8*)&s_e[(mt * 16 + l15) * ES + ch * 32 + quad * 8];
    #pragma unroll
    for (int mt = 0; mt < 4; ++mt)
      #pragma unroll
      for (int nt = 0; nt < 2; ++nt)
        acc[mt][nt] = __builtin_amdgcn_mfma_f32_16x16x32_bf16(
            a[mt], *(const bf16x8*)&bv[nt][ch * 8], acc[mt][nt], 0, 0, 0);
  }
  #pragma unroll
  for (int nt = 0; nt < 2; ++nt) {
    int col = wave * 32 + nt * 16 + l15;
    float bias = isY ? 0.f : b0[col];
    #pragma unroll
    for (int mt = 0; mt < 4; ++mt)
      #pragma unroll
      for (int rg = 0; rg < 4; ++rg) {
        int grow = row0 + mt * 16 + quad * 4 + rg;
        if (isY) { if (grow < N_Y) c_y[(size_t)grow * 128 + col] = f2bf(acc[mt][nt][rg]); }
        else     { c_x[(size_t)grow * 128 + col] = acc[mt][nt][rg] + bias; }
      }
  }
}

// ---- BARRIER-FREE edge kernel: each wave owns 16 edges end-to-end ----
// M-split at every layer: A-rows of layer L = the wave's own layer L-1 output.
// C->A layout transposes via a PRIVATE per-wave LDS patch (intra-wave DS
// ordering, no __syncthreads anywhere). Weight panels read per-wave (L1/L2 hot).
__global__ __launch_bounds__(256, 4) void fused_edge(
    const short* __restrict__ c_y, const float* __restrict__ c_x,
    const int* __restrict__ nidx, const float* __restrict__ f_y,
    const short* __restrict__ w1t, const float* __restrict__ b1,
    const short* __restrict__ w2t, const float* __restrict__ b2,
    const short* __restrict__ w3t, const float* __restrict__ b3,
    float* __restrict__ out)
{
  __shared__ __attribute__((aligned(16))) char smem[4][PBYTES];
  const int tid  = threadIdx.x;
  const int wave = tid >> 6, lane = tid & 63;
  const int quad = lane >> 4, l15 = lane & 15;
  short* patch = (short*)smem[wave];

  const int ew0 = blockIdx.x * 64 + wave * 16;   // this wave's first edge

  // ---- phase 0: h1 A-frags computed directly in-lane (no LDS, no barrier) ----
  // lane (quad,l15) needs h1[row=l15][k=ch*32+quad*8+j] for ch=0..3
  bf16x8 af[4];
  {
    const int idx = nidx[ew0 + l15];
    const short* cyr = c_y + (size_t)idx * 128 + quad * 8;
    const float* cxr = c_x + (size_t)((ew0 + l15) >> 3) * 128 + quad * 8;
    #pragma unroll
    for (int ch = 0; ch < 4; ++ch) {
      uint4 cy  = *(const uint4*)(cyr + ch * 32);
      float4 c0 = *(const float4*)(cxr + ch * 32);
      float4 c1 = *(const float4*)(cxr + ch * 32 + 4);
      const unsigned* cu = (const unsigned*)&cy;
      float cf[8] = {c0.x, c0.y, c0.z, c0.w, c1.x, c1.y, c1.z, c1.w};
      unsigned pk[4];
      #pragma unroll
      for (int p = 0; p < 4; ++p) {
        unsigned u = cu[p];
        float lo = __uint_as_float(u << 16)         + cf[2 * p];
        float hi = __uint_as_float(u & 0xffff0000u) + cf[2 * p + 1];
        pk[p] = pk_bf16(geluf(lo), geluf(hi));
      }
      af[ch] = *(bf16x8*)pk;
    }
  }

  // ---- layer 1: 16x128 @ 128x256 in two nt-halves (acc peak 32 VGPR) ----
  // h2 -> patch row-major [row*PS + col], written in C-layout, read as A-frags
  #pragma unroll
  for (int h = 0; h < 2; ++h) {
    f32x4 acc[8];
    #pragma unroll
    for (int nt = 0; nt < 8; ++nt) acc[nt] = (f32x4){0.f, 0.f, 0.f, 0.f};
    #pragma unroll
    for (int ch = 0; ch < 4; ++ch)
      #pragma unroll
      for (int nt = 0; nt < 8; ++nt) {
        bf16x8 b = *(const bf16x8*)&w1t[(size_t)((h * 8 + nt) * 16 + l15) * 128 + ch * 32 + quad * 8];
        acc[nt] = __builtin_amdgcn_mfma_f32_16x16x32_bf16(af[ch], b, acc[nt], 0, 0, 0);
      }
    #pragma unroll
    for (int nt = 0; nt < 8; ++nt) {
      int col = (h * 8 + nt) * 16 + l15;
      float bias = b1[col];
      #pragma unroll
      for (int rg = 0; rg < 4; ++rg)
        patch[(quad * 4 + rg) * PS + col] = f2bf(geluf(acc[nt][rg] + bias));
    }
  }

  // ---- layer 2: 16x256 @ 256x128; A from patch (b128 rows), h3 back to patch ----
  f32x4 acc2[8];
  #pragma unroll
  for (int nt = 0; nt < 8; ++nt) acc2[nt] = (f32x4){0.f, 0.f, 0.f, 0.f};
  #pragma unroll
  for (int ch = 0; ch < 8; ++ch) {
    bf16x8 a = *(const bf16x8*)&patch[l15 * PS + ch * 32 + quad * 8];
    #pragma unroll
    for (int nt = 0; nt < 8; ++nt) {
      bf16x8 b = *(const bf16x8*)&w2t[(size_t)(nt * 16 + l15) * 256 + ch * 32 + quad * 8];
      acc2[nt] = __builtin_amdgcn_mfma_f32_16x16x32_bf16(a, b, acc2[nt], 0, 0, 0);
    }
  }
  #pragma unroll
  for (int nt = 0; nt < 8; ++nt) {
    int col = nt * 16 + l15;
    float bias = b2[col];
    #pragma unroll
    for (int rg = 0; rg < 4; ++rg)
      patch[(quad * 4 + rg) * PS + col] = f2bf(geluf(acc2[nt][rg] + bias));  // h3
  }

  // ---- layer 3: 16x128 @ 128x32 linear -> kern (fp32 col-major in patch) ----
  f32x4 acc3[2];
  acc3[0] = (f32x4){0.f, 0.f, 0.f, 0.f};
  acc3[1] = (f32x4){0.f, 0.f, 0.f, 0.f};
  #pragma unroll
  for (int ch = 0; ch < 4; ++ch) {
    bf16x8 a = *(const bf16x8*)&patch[l15 * PS + ch * 32 + quad * 8];
    #pragma unroll
    for (int nt = 0; nt < 2; ++nt) {
      bf16x8 b = *(const bf16x8*)&w3t[(size_t)(nt * 16 + l15) * 128 + ch * 32 + quad * 8];
      acc3[nt] = __builtin_amdgcn_mfma_f32_16x16x32_bf16(a, b, acc3[nt], 0, 0, 0);
    }
  }
  float* kf = (float*)patch;
  #pragma unroll
  for (int nt = 0; nt < 2; ++nt) {
    int col = nt * 16 + l15;
    float bias = b3[col];
    f32x4 v;
    #pragma unroll
    for (int rg = 0; rg < 4; ++rg) v[rg] = acc3[nt][rg] + bias;
    *(f32x4*)&kf[col * KFS + quad * 4] = v;      // 16B-aligned (KFS*4=80, quad*16)
  }

  // ---- reduce: wave's 2 x-points; kern rows are the wave's own 16 edges ----
  {
    const int xl = lane >> 5, cc = lane & 31;
    f32x4 k0 = *(const f32x4*)&kf[cc * KFS + xl * 8];
    f32x4 k1 = *(const f32x4*)&kf[cc * KFS + xl * 8 + 4];
    float acc[TDIM] = {0.f, 0.f, 0.f, 0.f};
    #pragma unroll
    for (int j = 0; j < KNBR; ++j) {
      int idxj = nidx[ew0 + xl * 8 + j];
      const float* fp = f_y + (size_t)idxj * CDIM + cc;
      float kv = (j < 4) ? k0[j] : k1[j - 4];
      #pragma unroll
      for (int t = 0; t < TDIM; ++t)
        acc[t] += kv * fp[(size_t)t * N_Y * CDIM];
    }
    const int xg = blockIdx.x * 8 + wave * 2 + xl;
    #pragma unroll
    for (int t = 0; t < TDIM; ++t)
      out[((size_t)t * N_X + xg) * CDIM + cc] = acc[t];
  }
}

extern "C" void kernel_launch(void* const* d_in, const int* in_sizes, int n_in,
                              void* d_out, int out_size, void* d_ws, size_t ws_size,
                              hipStream_t stream)
{
  const float* y   = (const float*)d_in[0];
  const float* x   = (const float*)d_in[1];
  const float* f_y = (const float*)d_in[2];
  const int*  nidx = (const int*)d_in[3];
  const float* W0 = (const float*)d_in[4];  const float* b0 = (const float*)d_in[5];
  const float* W1 = (const float*)d_in[6];  const float* b1 = (const float*)d_in[7];
  const float* W2 = (const float*)d_in[8];  const float* b2 = (const float*)d_in[9];
  const float* W3 = (const float*)d_in[10]; const float* b3 = (const float*)d_in[11];

  char* ws = (char*)d_ws;
  short* c_y  = (short*)(ws + 0);           // 50000*128*2  = 12,800,000
  float* c_x  = (float*)(ws + 12800000);    // 32768*128*4  = 16,777,216
  short* w1t  = (short*)(ws + 29577216);    // 256*128*2
  short* w2t  = (short*)(ws + 29642752);    // 128*256*2
  short* w3t  = (short*)(ws + 29708288);    //  32*128*2

  hipLaunchKernelGGL(prep_all, dim3(PREP_NB), dim3(256), 0, stream,
                     y, x, W0, b0, W1, W2, W3, w1t, w2t, w3t, c_y, c_x);
  hipLaunchKernelGGL(fused_edge, dim3(ECNT / 64), dim3(256), 0, stream,
                     c_y, c_x, nidx, f_y, w1t, b1, w2t, b2, w3t, b3, (float*)d_out);
}

// Round 11
// 242.593 us; speedup vs baseline: 1.5117x; 1.5117x over previous
//
#include <hip/hip_runtime.h>
#include <stdint.h>

#define EMB_DIM 192
#define CDIM 32
#define TDIM 4
#define N_Y 50000
#define N_X 32768
#define KNBR 8
#define ECNT (N_X*KNBR)  // 262144

// LDS row strides (shorts), odd-word -> low conflicts (proven R3-R5)
#define H1S 134
#define H2S 262
#define KS  33
#define ES  200

// prep_all block ranges
#define PREP_TW 272
#define PREP_Y0 PREP_TW
#define PREP_X0 (PREP_TW + 782)
#define PREP_NB (PREP_TW + 782 + 512)

typedef __attribute__((ext_vector_type(8))) short bf16x8;
typedef __attribute__((ext_vector_type(4))) float f32x4;

static __device__ __forceinline__ short f2bf(float f){
  unsigned u = __float_as_uint(f);
  return (short)((u + 0x7FFFu) >> 16);
}
static __device__ __forceinline__ unsigned pk_bf16(float lo, float hi){
  return ((__float_as_uint(lo) + 0x7FFFu) >> 16) |
         ((((__float_as_uint(hi) + 0x7FFFu) >> 16)) << 16);
}
static __device__ __forceinline__ float geluf(float x){
  float x2 = x * x;
  float u  = __builtin_fmaf(0.044715f, x2, 1.0f);
  float p  = x * -1.5957691216057308f;      // -2*0.7978845608
  float e  = __expf(p * u);                 // exp(-2t)
  return x * __builtin_amdgcn_rcpf(1.0f + e);
}

// ---- ONE prep kernel (R9, proven): transpose w1/w2/w3 + precompute c_y/c_x ----
__global__ __launch_bounds__(256, 2) void prep_all(
    const float* __restrict__ ypts, const float* __restrict__ xpts,
    const float* __restrict__ W0, const float* __restrict__ b0,
    const float* __restrict__ W1, const float* __restrict__ W2,
    const float* __restrict__ W3,
    short* __restrict__ w1t, short* __restrict__ w2t, short* __restrict__ w3t,
    short* __restrict__ c_y, float* __restrict__ c_x)
{
  const int tid = threadIdx.x;
  if (blockIdx.x < PREP_TW) {
    int id = blockIdx.x * 256 + tid;
    if (id < 32768) {                     // w1t[n*128+k] = W1[k][n] (128x256)
      int n = id >> 7, k = id & 127;
      w1t[id] = f2bf(W1[k * 256 + n]);
    } else if (id < 65536) {              // w2t[n*256+k] = W2[k][n] (256x128)
      int loc = id - 32768; int n = loc >> 8, k = loc & 255;
      w2t[loc] = f2bf(W2[k * 128 + n]);
    } else if (id < 69632) {              // w3t[n*128+k] = W3[k][n] (128x32)
      int loc = id - 65536; int n = loc >> 7, k = loc & 127;
      w3t[loc] = f2bf(W3[k * 32 + n]);
    }
    return;
  }

  __shared__ __attribute__((aligned(16))) short s_e[64 * ES];
  const bool isY = blockIdx.x < PREP_X0;
  const int row0 = isY ? (blockIdx.x - PREP_Y0) * 64 : (blockIdx.x - PREP_X0) * 64;
  const int wave = tid >> 6, lane = tid & 63;
  const int quad = lane >> 4, l15 = lane & 15;
  const float* W0h = W0 + (isY ? 0 : 192 * 128);

  short bv[2][48];
  #pragma unroll
  for (int nt = 0; nt < 2; ++nt) {
    int n = wave * 32 + nt * 16 + l15;
    #pragma unroll
    for (int ch = 0; ch < 6; ++ch)
      #pragma unroll
      for (int j = 0; j < 8; ++j)
        bv[nt][ch * 8 + j] = f2bf(W0h[(size_t)(ch * 32 + quad * 8 + j) * 128 + n]);
  }

  {
    const int r = tid >> 2, q = tid & 3;
    const int grow = row0 + r;
    const bool valid = isY ? (grow < N_Y) : true;
    const float* src = isY ? (ypts + (size_t)grow * 3) : (xpts + (size_t)grow * 3);
    float c[3] = {0.f, 0.f, 0.f};
    if (valid) { c[0] = src[0]; c[1] = src[1]; c[2] = src[2]; }
    #pragma unroll
    for (int j = 0; j < 24; ++j) {
      int p = q * 24 + j;
      int d = p >> 5, i = p & 31;
      float f = __expf(-0.28782313662425575f * (float)i);   // (1e-4)^(i/32)
      float rev = c[d] * f * 0.15915494309189535f;
      float s  = __builtin_amdgcn_sinf(rev);
      float co = __builtin_amdgcn_cosf(rev);
      *(unsigned*)&s_e[r * ES + d * 64 + 2 * i] = pk_bf16(s, co);
    }
  }
  __syncthreads();

  f32x4 acc[4][2];
  #pragma unroll
  for (int mt = 0; mt < 4; ++mt)
    #pragma unroll
    for (int nt = 0; nt < 2; ++nt) acc[mt][nt] = (f32x4){0.f, 0.f, 0.f, 0.f};
  #pragma unroll
  for (int ch = 0; ch < 6; ++ch) {
    bf16x8 a[4];
    #pragma unroll
    for (int mt = 0; mt < 4; ++mt)
      a[mt] = *(const bf16x8*)&s_e[(mt * 16 + l15) * ES + ch * 32 + quad * 8];
    #pragma unroll
    for (int mt = 0; mt < 4; ++mt)
      #pragma unroll
      for (int nt = 0; nt < 2; ++nt)
        acc[mt][nt] = __builtin_amdgcn_mfma_f32_16x16x32_bf16(
            a[mt], *(const bf16x8*)&bv[nt][ch * 8], acc[mt][nt], 0, 0, 0);
  }
  #pragma unroll
  for (int nt = 0; nt < 2; ++nt) {
    int col = wave * 32 + nt * 16 + l15;
    float bias = isY ? 0.f : b0[col];
    #pragma unroll
    for (int mt = 0; mt < 4; ++mt)
      #pragma unroll
      for (int rg = 0; rg < 4; ++rg) {
        int grow = row0 + mt * 16 + quad * 4 + rg;
        if (isY) { if (grow < N_Y) c_y[(size_t)grow * 128 + col] = f2bf(acc[mt][nt][rg]); }
        else     { c_x[(size_t)grow * 128 + col] = acc[mt][nt][rg] + bias; }
      }
  }
}

// ---- edge kernel: R9 structure, barrier-4 removed (intra-wave kern handoff)
//      + early f_y gather issue (crosses no barriers -> no spill) ----
// region1 [0,33536): h2 (64xH2S bf16), later kern (64xKS f32)
// region2 [33536,50688): h1 (64xH1S bf16), later h3
__global__ __launch_bounds__(256, 3) void fused_edge(
    const short* __restrict__ c_y, const float* __restrict__ c_x,
    const int* __restrict__ nidx, const float* __restrict__ f_y,
    const short* __restrict__ w1t, const float* __restrict__ b1,
    const short* __restrict__ w2t, const float* __restrict__ b2,
    const short* __restrict__ w3t, const float* __restrict__ b3,
    float* __restrict__ out)
{
  __shared__ __attribute__((aligned(16))) char smem[50688];
  short* s_h2   = (short*)smem;
  float* s_kern = (float*)smem;
  short* s_h1   = (short*)(smem + 33536);

  const int tid  = threadIdx.x;
  const int e0   = blockIdx.x * 64;
  const int wave = tid >> 6, lane = tid & 63;
  const int quad = lane >> 4, l15 = lane & 15;

  // ---- phase 0: h1 = gelu(c_y[idx] + c_x[e>>3]) ----
  {
    const int r = tid >> 2, q = tid & 3;
    const int idx = nidx[e0 + r];
    const uint4*  cyp = (const uint4*)(c_y + (size_t)idx * 128 + q * 32);
    const float4* cxp = (const float4*)(c_x + (size_t)((e0 + r) >> 3) * 128 + q * 32);
    uint4  cyv[4];
    float4 cxv[8];
    #pragma unroll
    for (int i = 0; i < 4; ++i) cyv[i] = cyp[i];
    #pragma unroll
    for (int i = 0; i < 8; ++i) cxv[i] = cxp[i];
    const float* cxa = (const float*)cxv;
    const unsigned* cya = (const unsigned*)cyv;
    unsigned pk[16];
    #pragma unroll
    for (int jj = 0; jj < 16; ++jj) {
      unsigned u = cya[jj];
      float lo = __uint_as_float(u << 16)         + cxa[2 * jj];
      float hi = __uint_as_float(u & 0xffff0000u) + cxa[2 * jj + 1];
      pk[jj] = pk_bf16(geluf(lo), geluf(hi));
    }
    uint4* dst = (uint4*)&s_h1[r * H1S + q * 32];
    #pragma unroll
    for (int jj = 0; jj < 4; ++jj)
      dst[jj] = *(uint4*)&pk[jj * 4];
  }
  __syncthreads();

  // ---------- layer 1: 128 -> 256, GELU (wave owns 64 cols) ----------
  {
    f32x4 acc1[4][4];
    #pragma unroll
    for (int mt = 0; mt < 4; ++mt)
      #pragma unroll
      for (int nt = 0; nt < 4; ++nt) acc1[mt][nt] = (f32x4){0.f, 0.f, 0.f, 0.f};
    #pragma unroll
    for (int ch = 0; ch < 4; ++ch) {
      bf16x8 a[4], b[4];
      #pragma unroll
      for (int mt = 0; mt < 4; ++mt)
        a[mt] = *(const bf16x8*)&s_h1[(mt * 16 + l15) * H1S + ch * 32 + quad * 8];
      #pragma unroll
      for (int nt = 0; nt < 4; ++nt)
        b[nt] = *(const bf16x8*)&w1t[(size_t)(wave * 64 + nt * 16 + l15) * 128 + ch * 32 + quad * 8];
      #pragma unroll
      for (int mt = 0; mt < 4; ++mt)
        #pragma unroll
        for (int nt = 0; nt < 4; ++nt)
          acc1[mt][nt] = __builtin_amdgcn_mfma_f32_16x16x32_bf16(a[mt], b[nt], acc1[mt][nt], 0, 0, 0);
    }
    #pragma unroll
    for (int nt = 0; nt < 4; ++nt) {
      int col = wave * 64 + nt * 16 + l15;
      float bias = b1[col];
      #pragma unroll
      for (int mt = 0; mt < 4; ++mt)
        #pragma unroll
        for (int rg = 0; rg < 4; ++rg) {
          int row = mt * 16 + quad * 4 + rg;
          s_h2[row * H2S + col] = f2bf(geluf(acc1[mt][nt][rg] + bias));
        }
    }
  }
  __syncthreads();   // h2 visible; h1 reads done -> h3 may overwrite region2

  // ---------- layer 2: 256 -> 128, GELU (wave owns 32 cols) ----------
  {
    f32x4 acc2[4][2];
    #pragma unroll
    for (int mt = 0; mt < 4; ++mt)
      #pragma unroll
      for (int nt = 0; nt < 2; ++nt) acc2[mt][nt] = (f32x4){0.f, 0.f, 0.f, 0.f};
    #pragma unroll
    for (int ch = 0; ch < 8; ++ch) {
      bf16x8 a[4], b[2];
      #pragma unroll
      for (int mt = 0; mt < 4; ++mt)
        a[mt] = *(const bf16x8*)&s_h2[(mt * 16 + l15) * H2S + ch * 32 + quad * 8];
      #pragma unroll
      for (int nt = 0; nt < 2; ++nt)
        b[nt] = *(const bf16x8*)&w2t[(size_t)(wave * 32 + nt * 16 + l15) * 256 + ch * 32 + quad * 8];
      #pragma unroll
      for (int mt = 0; mt < 4; ++mt)
        #pragma unroll
        for (int nt = 0; nt < 2; ++nt)
          acc2[mt][nt] = __builtin_amdgcn_mfma_f32_16x16x32_bf16(a[mt], b[nt], acc2[mt][nt], 0, 0, 0);
    }
    #pragma unroll
    for (int nt = 0; nt < 2; ++nt) {
      int col = wave * 32 + nt * 16 + l15;
      float bias = b2[col];
      #pragma unroll
      for (int mt = 0; mt < 4; ++mt)
        #pragma unroll
        for (int rg = 0; rg < 4; ++rg) {
          int row = mt * 16 + quad * 4 + rg;
          s_h1[row * H1S + col] = f2bf(geluf(acc2[mt][nt][rg] + bias));   // h3
        }
    }
  }
  __syncthreads();   // h3 visible; h2 reads done -> kern may overwrite region1

  // ---- early f_y gather issue: consumed after layer 3 (no barrier crossed) ----
  const int xloc = tid >> 5;       // wave-local x-point: 2*wave + (lane>>5)
  const int cc   = tid & 31;
  float fv[KNBR * TDIM];
  {
    const int ebase = xloc * 8;
    #pragma unroll
    for (int j = 0; j < KNBR; ++j) {
      int idxj = nidx[e0 + ebase + j];
      const float* fp = f_y + (size_t)idxj * CDIM + cc;
      #pragma unroll
      for (int t = 0; t < TDIM; ++t)
        fv[j * TDIM + t] = fp[(size_t)t * N_Y * CDIM];
    }
  }

  // ---------- layer 3: 128 -> 32 linear (wave owns 16 rows) -> s_kern ----------
  {
    f32x4 acc3[2];
    acc3[0] = (f32x4){0.f, 0.f, 0.f, 0.f};
    acc3[1] = (f32x4){0.f, 0.f, 0.f, 0.f};
    #pragma unroll
    for (int ch = 0; ch < 4; ++ch) {
      bf16x8 a3 = *(const bf16x8*)&s_h1[(wave * 16 + l15) * H1S + ch * 32 + quad * 8];
      #pragma unroll
      for (int nt = 0; nt < 2; ++nt) {
        bf16x8 b3f = *(const bf16x8*)&w3t[(size_t)(nt * 16 + l15) * 128 + ch * 32 + quad * 8];
        acc3[nt] = __builtin_amdgcn_mfma_f32_16x16x32_bf16(a3, b3f, acc3[nt], 0, 0, 0);
      }
    }
    #pragma unroll
    for (int nt = 0; nt < 2; ++nt) {
      int col = nt * 16 + l15;
      float bias = b3[col];
      #pragma unroll
      for (int rg = 0; rg < 4; ++rg) {
        int row = wave * 16 + quad * 4 + rg;
        s_kern[row * KS + col] = acc3[nt][rg] + bias;
      }
    }
  }
  // NO __syncthreads here: wave w wrote s_kern rows [16w,16w+16) and the reduce
  // below reads only rows [xloc*8, xloc*8+8) = the SAME wave's rows. Intra-wave
  // DS ordering + lgkmcnt drain is the exact contract (no vmcnt drain -> the
  // fv gathers above stay in flight).
  asm volatile("s_waitcnt lgkmcnt(0)" ::: "memory");

  // ---------- fused reduce (f_y pre-gathered in fv) ----------
  {
    float acc[TDIM] = {0.f, 0.f, 0.f, 0.f};
    const int ebase = xloc * 8;
    #pragma unroll
    for (int j = 0; j < KNBR; ++j) {
      float kv = s_kern[(ebase + j) * KS + cc];
      #pragma unroll
      for (int t = 0; t < TDIM; ++t)
        acc[t] += kv * fv[j * TDIM + t];
    }
    const int xg = blockIdx.x * 8 + xloc;
    #pragma unroll
    for (int t = 0; t < TDIM; ++t)
      out[((size_t)t * N_X + xg) * CDIM + cc] = acc[t];
  }
}

extern "C" void kernel_launch(void* const* d_in, const int* in_sizes, int n_in,
                              void* d_out, int out_size, void* d_ws, size_t ws_size,
                              hipStream_t stream)
{
  const float* y   = (const float*)d_in[0];
  const float* x   = (const float*)d_in[1];
  const float* f_y = (const float*)d_in[2];
  const int*  nidx = (const int*)d_in[3];
  const float* W0 = (const float*)d_in[4];  const float* b0 = (const float*)d_in[5];
  const float* W1 = (const float*)d_in[6];  const float* b1 = (const float*)d_in[7];
  const float* W2 = (const float*)d_in[8];  const float* b2 = (const float*)d_in[9];
  const float* W3 = (const float*)d_in[10]; const float* b3 = (const float*)d_in[11];

  char* ws = (char*)d_ws;
  short* c_y  = (short*)(ws + 0);           // 50000*128*2  = 12,800,000
  float* c_x  = (float*)(ws + 12800000);    // 32768*128*4  = 16,777,216
  short* w1t  = (short*)(ws + 29577216);    // 256*128*2
  short* w2t  = (short*)(ws + 29642752);    // 128*256*2
  short* w3t  = (short*)(ws + 29708288);    //  32*128*2

  hipLaunchKernelGGL(prep_all, dim3(PREP_NB), dim3(256), 0, stream,
                     y, x, W0, b0, W1, W2, W3, w1t, w2t, w3t, c_y, c_x);
  hipLaunchKernelGGL(fused_edge, dim3(ECNT / 64), dim3(256), 0, stream,
                     c_y, c_x, nidx, f_y, w1t, b1, w2t, b2, w3t, b3, (float*)d_out);
}